// Round 15
// baseline (211.668 us; speedup 1.0000x reference)
//
#include <hip/hip_runtime.h>
#include <stdint.h>

#define N1 8192
#define N2 8192
#define DK 128
#define TAU 0.08f     // repair margin (sim units); ~15-20 sigma of f16 dot noise

typedef _Float16 half8 __attribute__((ext_vector_type(8)));
typedef __fp16 fp16x2 __attribute__((ext_vector_type(2)));
typedef float floatx4 __attribute__((ext_vector_type(4)));

// Module-scope device scratch (graph-capture safe). Fully rewritten each launch.
__device__ __align__(16) uint2 g_rowtop2[64 * N1];      // 4 MB [128colgrp][row] tile-owned
__device__ __align__(16) uint2 g_coltop2[64 * N2];      // 4 MB [128rowgrp][col]
__device__ int g_nn21[N2];

// order-preserving f32 <-> u32
__device__ __forceinline__ unsigned mono32(float v) {
    unsigned u = __float_as_uint(v);
    return u ^ ((u & 0x80000000u) ? 0xFFFFFFFFu : 0x80000000u);
}
__device__ __forceinline__ float unmono32(unsigned k) {
    unsigned u = (k & 0x80000000u) ? (k ^ 0x80000000u) : ~k;
    return __uint_as_float(u);
}
// key: monotone value bits, low 7 bits = idx within 128-group (quant ~6e-4 << TAU)
__device__ __forceinline__ unsigned qkey(float v, unsigned idx) {
    return (mono32(v) & 0xFFFFFF80u) | idx;
}
__device__ __forceinline__ void push2u(unsigned& t1, unsigned& t2, unsigned p) {
    unsigned lo = min(t1, p);
    t1 = max(t1, p);
    t2 = max(t2, lo);
}
__device__ __forceinline__ void merge2u(unsigned& t1, unsigned& t2, unsigned o1, unsigned o2) {
    unsigned n1 = max(t1, o1);
    unsigned n2 = max(min(t1, o1), max(t2, o2));
    t1 = n1; t2 = n2;
}
__device__ __forceinline__ unsigned long long pack64(float d, unsigned idx) {
    return ((unsigned long long)mono32(d) << 32) | (unsigned)(~idx);
}
// 8x f32 -> f16 fragment via v_cvt_pkrtz (round-to-zero; approx-GEMM only feeds
// candidate selection, repair uses exact fp32 -> rounding mode irrelevant).
__device__ __forceinline__ half8 cvt8(float4 lo, float4 hi) {
    fp16x2 p0 = __builtin_amdgcn_cvt_pkrtz(lo.x, lo.y);
    fp16x2 p1 = __builtin_amdgcn_cvt_pkrtz(lo.z, lo.w);
    fp16x2 p2 = __builtin_amdgcn_cvt_pkrtz(hi.x, hi.y);
    fp16x2 p3 = __builtin_amdgcn_cvt_pkrtz(hi.z, hi.w);
    union { fp16x2 h2[4]; half8 h8; } u;
    u.h2[0] = p0; u.h2[1] = p1; u.h2[2] = p2; u.h2[3] = p3;
    return u.h8;
}

// 128x128 tile per block, 4 waves. fp32 loaded directly, f16 fragments built
// in-register (no staging kernel). Direct-global fragments (R11), 128-group
// LDS-merged top2 epilogue (R8/R13), XCD swizzle. Unbounded regs (R13 lesson:
// min-waves=4 spilled acc; R11's no-bound 84-VGPR regime is the proven one).
__global__ __launch_bounds__(256) void simf16_kernel(const float* __restrict__ A,
                                                     const float* __restrict__ B) {
    __shared__ uint2 lmerge[2][128];   // 2 KB

    const int tid  = threadIdx.x;
    const int lane = tid & 63;
    const int wave = tid >> 6;
    const int wm = wave >> 1, wn = wave & 1;
    const int fr = lane & 15, q = lane >> 4;

    // XCD swizzle: dispatch-neighbors (round-robin over 8 XCDs) share ty,
    // clustered tx -> per-XCD L2 panel reuse.
    const int flat = blockIdx.y * 64 + blockIdx.x;
    const int xcd = flat & 7;
    const int j = flat >> 3;
    const int ty = j >> 3;
    const int tx = ((j & 7) << 3) | xcd;
    const int row0 = ty * 128, col0 = tx * 128;

    floatx4 acc[4][4];
#pragma unroll
    for (int mt = 0; mt < 4; ++mt)
#pragma unroll
        for (int nt = 0; nt < 4; ++nt)
            acc[mt][nt] = (floatx4){0.f, 0.f, 0.f, 0.f};

    const float* Ab = A + (size_t)(row0 + wm * 64 + fr) * DK + q * 8;
    const float* Bb = B + (size_t)(col0 + wn * 64 + fr) * DK + q * 8;

#pragma unroll
    for (int ks = 0; ks < 4; ++ks) {
        half8 af[4], bf[4];
#pragma unroll
        for (int mt = 0; mt < 4; ++mt) {
            const float* p = Ab + mt * 16 * DK + ks * 32;
            af[mt] = cvt8(*reinterpret_cast<const float4*>(p),
                          *reinterpret_cast<const float4*>(p + 4));
        }
#pragma unroll
        for (int nt = 0; nt < 4; ++nt) {
            const float* p = Bb + nt * 16 * DK + ks * 32;
            bf[nt] = cvt8(*reinterpret_cast<const float4*>(p),
                          *reinterpret_cast<const float4*>(p + 4));
        }
#pragma unroll
        for (int mt = 0; mt < 4; ++mt)
#pragma unroll
            for (int nt = 0; nt < 4; ++nt)
                acc[mt][nt] = __builtin_amdgcn_mfma_f32_16x16x32_f16(af[mt], bf[nt], acc[mt][nt], 0, 0, 0);
    }

    // ---- row phase: top2 over 128 cols (C/D: col=lane&15, row=q*4+reg) ----
#pragma unroll
    for (int mt = 0; mt < 4; ++mt) {
#pragma unroll
        for (int reg = 0; reg < 4; ++reg) {
            unsigned t1 = 0u, t2 = 0u;
#pragma unroll
            for (int nt = 0; nt < 4; ++nt)
                push2u(t1, t2, qkey(acc[mt][nt][reg], (unsigned)(wn * 64 + nt * 16 + fr)));
#pragma unroll
            for (int off = 1; off < 16; off <<= 1) {
                unsigned o1 = __shfl_xor(t1, off, 64);
                unsigned o2 = __shfl_xor(t2, off, 64);
                merge2u(t1, t2, o1, o2);
            }
            if (fr == 0) lmerge[wn][wm * 64 + mt * 16 + q * 4 + reg] = make_uint2(t1, t2);
        }
    }
    __syncthreads();
    if (tid < 128) {
        uint2 a = lmerge[0][tid], b = lmerge[1][tid];
        merge2u(a.x, a.y, b.x, b.y);
        g_rowtop2[(size_t)tx * N1 + row0 + tid] = a;   // contiguous 1 KB run
    }
    __syncthreads();

    // ---- col phase: top2 over 128 rows ----
#pragma unroll
    for (int nt = 0; nt < 4; ++nt) {
        unsigned t1 = 0u, t2 = 0u;
#pragma unroll
        for (int mt = 0; mt < 4; ++mt)
#pragma unroll
            for (int reg = 0; reg < 4; ++reg)
                push2u(t1, t2, qkey(acc[mt][nt][reg], (unsigned)(wm * 64 + mt * 16 + q * 4 + reg)));
        unsigned o1 = __shfl_xor(t1, 16, 64), o2 = __shfl_xor(t2, 16, 64);
        merge2u(t1, t2, o1, o2);
        o1 = __shfl_xor(t1, 32, 64); o2 = __shfl_xor(t2, 32, 64);
        merge2u(t1, t2, o1, o2);
        if (q == 0) lmerge[wm][wn * 64 + nt * 16 + fr] = make_uint2(t1, t2);
    }
    __syncthreads();
    if (tid < 128) {
        uint2 a = lmerge[0][tid], b = lmerge[1][tid];
        merge2u(a.x, a.y, b.x, b.y);
        g_coltop2[(size_t)ty * N2 + col0 + tid] = a;
    }
}

// 16 cols per block (512 blocks). Candidates within TAU of approx max get the
// fp32 SEQUENTIAL k-ascending fmaf chain (bitwise reference rounding, R6-proven).
__global__ __launch_bounds__(256) void colfix_kernel(const float* __restrict__ A,
                                                     const float* __restrict__ B) {
    __shared__ uint2 tile[64 * 16];           // 8 KB
    __shared__ unsigned long long slot[16];
    __shared__ int cand[256];
    __shared__ int cand_cnt;

    const int tid = threadIdx.x;
    const int c0 = blockIdx.x * 16;

#pragma unroll
    for (int i = 0; i < 4; ++i) {
        int idx = i * 256 + tid;              // 0..1023
        int grp = idx >> 4, c = idx & 15;
        tile[grp * 16 + c] = g_coltop2[(size_t)grp * N2 + c0 + c];
    }
    if (tid < 16) slot[tid] = 0ULL;
    if (tid == 0) cand_cnt = 0;
    __syncthreads();

    const int c = tid >> 4, j = tid & 15;     // 16 threads per col, 4 grps each
    float mx = -1e30f;
#pragma unroll
    for (int s = 0; s < 4; ++s) {
        uint2 e = tile[(j * 4 + s) * 16 + c];
        mx = fmaxf(mx, unmono32(e.x & 0xFFFFFF80u));
    }
    mx = fmaxf(mx, __shfl_xor(mx, 1, 64));
    mx = fmaxf(mx, __shfl_xor(mx, 2, 64));
    mx = fmaxf(mx, __shfl_xor(mx, 4, 64));
    mx = fmaxf(mx, __shfl_xor(mx, 8, 64));
    const float thr = mx - TAU;
#pragma unroll
    for (int s = 0; s < 4; ++s) {
        int grp = j * 4 + s;
        uint2 e = tile[grp * 16 + c];
        if (unmono32(e.x & 0xFFFFFF80u) >= thr) {
            int rr = grp * 128 + (int)(e.x & 127u);
            int si = atomicAdd(&cand_cnt, 1);
            if (si < 256) cand[si] = (c << 16) | rr;
        }
        if (unmono32(e.y & 0xFFFFFF80u) >= thr) {
            int rr = grp * 128 + (int)(e.y & 127u);
            int si = atomicAdd(&cand_cnt, 1);
            if (si < 256) cand[si] = (c << 16) | rr;
        }
    }
    __syncthreads();

    const int nc = min(cand_cnt, 256);
    for (int i = tid; i < nc; i += 256) {
        int pc = cand[i];
        int cl = pc >> 16, rr = pc & 0xFFFF;
        const float* ar = A + (size_t)rr * DK;
        const float* br = B + (size_t)(c0 + cl) * DK;
        float d = 0.0f;
#pragma unroll
        for (int k4 = 0; k4 < DK / 4; ++k4) {
            float4 a = *reinterpret_cast<const float4*>(ar + k4 * 4);
            float4 b = *reinterpret_cast<const float4*>(br + k4 * 4);
            d = fmaf(a.x, b.x, d);
            d = fmaf(a.y, b.y, d);
            d = fmaf(a.z, b.z, d);
            d = fmaf(a.w, b.w, d);
        }
        atomicMax(&slot[cl], pack64(d, (unsigned)rr));
    }
    __syncthreads();

    if (tid < 16) g_nn21[c0 + tid] = (int)(~(unsigned)slot[tid]);
}

// 16 rows per block (512 blocks). Same repair; fuses mutual check (g_nn21
// complete from the prior colfix launch) and writes both outputs.
__global__ __launch_bounds__(256) void rowfix_mutual_kernel(const float* __restrict__ A,
                                                            const float* __restrict__ B,
                                                            float* __restrict__ out) {
    __shared__ uint2 tile[64 * 16];
    __shared__ unsigned long long slot[16];
    __shared__ int cand[256];
    __shared__ int cand_cnt;

    const int tid = threadIdx.x;
    const int r0 = blockIdx.x * 16;

#pragma unroll
    for (int i = 0; i < 4; ++i) {
        int idx = i * 256 + tid;
        int grp = idx >> 4, r = idx & 15;
        tile[grp * 16 + r] = g_rowtop2[(size_t)grp * N1 + r0 + r];
    }
    if (tid < 16) slot[tid] = 0ULL;
    if (tid == 0) cand_cnt = 0;
    __syncthreads();

    const int r = tid >> 4, j = tid & 15;
    float mx = -1e30f;
#pragma unroll
    for (int s = 0; s < 4; ++s) {
        uint2 e = tile[(j * 4 + s) * 16 + r];
        mx = fmaxf(mx, unmono32(e.x & 0xFFFFFF80u));
    }
    mx = fmaxf(mx, __shfl_xor(mx, 1, 64));
    mx = fmaxf(mx, __shfl_xor(mx, 2, 64));
    mx = fmaxf(mx, __shfl_xor(mx, 4, 64));
    mx = fmaxf(mx, __shfl_xor(mx, 8, 64));
    const float thr = mx - TAU;
#pragma unroll
    for (int s = 0; s < 4; ++s) {
        int grp = j * 4 + s;
        uint2 e = tile[grp * 16 + r];
        if (unmono32(e.x & 0xFFFFFF80u) >= thr) {
            int cc = grp * 128 + (int)(e.x & 127u);
            int si = atomicAdd(&cand_cnt, 1);
            if (si < 256) cand[si] = (r << 16) | cc;
        }
        if (unmono32(e.y & 0xFFFFFF80u) >= thr) {
            int cc = grp * 128 + (int)(e.y & 127u);
            int si = atomicAdd(&cand_cnt, 1);
            if (si < 256) cand[si] = (r << 16) | cc;
        }
    }
    __syncthreads();

    const int nc = min(cand_cnt, 256);
    for (int i = tid; i < nc; i += 256) {
        int pc = cand[i];
        int rl = pc >> 16, cc = pc & 0xFFFF;
        const float* ar = A + (size_t)(r0 + rl) * DK;
        const float* br = B + (size_t)cc * DK;
        float d = 0.0f;
#pragma unroll
        for (int k4 = 0; k4 < DK / 4; ++k4) {
            float4 a = *reinterpret_cast<const float4*>(ar + k4 * 4);
            float4 b = *reinterpret_cast<const float4*>(br + k4 * 4);
            d = fmaf(a.x, b.x, d);
            d = fmaf(a.y, b.y, d);
            d = fmaf(a.z, b.z, d);
            d = fmaf(a.w, b.w, d);
        }
        atomicMax(&slot[rl], pack64(d, (unsigned)cc));
    }
    __syncthreads();

    if (tid < 16) {
        unsigned long long p = slot[tid];
        int row = r0 + tid;
        int m = (int)(~(unsigned)p);
        out[row] = (float)((g_nn21[m] == row) ? m : -1);     // matches0
        out[N1 + row] = unmono32((unsigned)(p >> 32));       // exact score
    }
}

extern "C" void kernel_launch(void* const* d_in, const int* in_sizes, int n_in,
                              void* d_out, int out_size, void* d_ws, size_t ws_size,
                              hipStream_t stream) {
    const float* A = (const float*)d_in[0];   // desc1 [8192,128] f32
    const float* B = (const float*)d_in[1];   // desc2 [8192,128] f32
    float* out = (float*)d_out;               // [0:8192]=matches, [8192:16384]=scores

    dim3 grid(64, 64);
    simf16_kernel<<<grid, 256, 0, stream>>>(A, B);
    colfix_kernel<<<N2 / 16, 256, 0, stream>>>(A, B);
    rowfix_mutual_kernel<<<N1 / 16, 256, 0, stream>>>(A, B, out);
}

// Round 16
// 136.450 us; speedup vs baseline: 1.5512x; 1.5512x over previous
//
#include <hip/hip_runtime.h>
#include <stdint.h>

#define N1 8192
#define N2 8192
#define DK 128
#define TAU 0.08f     // repair margin (sim units); ~15 sigma of f16 dot noise
#define BIAS 256.0f   // sim in [-70,70] -> biased keys are positive floats

typedef _Float16 half8 __attribute__((ext_vector_type(8)));
typedef _Float16 half4 __attribute__((ext_vector_type(4)));
typedef float floatx4 __attribute__((ext_vector_type(4)));

// Module-scope device scratch (graph-capture safe). Fully rewritten each launch.
__device__ __align__(16) _Float16 g_Af[N1 * DK];        // 2 MB
__device__ __align__(16) _Float16 g_Bf[N2 * DK];        // 2 MB
__device__ __align__(16) float2 g_rowtop2[64 * N1];     // 4 MB [128colgrp][row] tile-owned
__device__ __align__(16) float2 g_coltop2[64 * N2];     // 4 MB [128rowgrp][col]
__device__ int g_nn21[N2];

// ---- biased-float keys (group top2; quant <= 3.9e-3 << TAU) ----
// key = float bits of (v+BIAS) with low 7 bits = idx-in-128-group.
// Positive floats: float order == unsigned bit order, so fmaxf/fmed3 work.
__device__ __forceinline__ float bkey(float v, unsigned idx) {
    unsigned b = __float_as_uint(v + BIAS);
    return __uint_as_float((b & 0xFFFFFF80u) | idx);
}
__device__ __forceinline__ float bval(float key) {      // biased-domain value
    return __uint_as_float(__float_as_uint(key) & 0xFFFFFF80u);
}
__device__ __forceinline__ int bidx(float key) {
    return (int)(__float_as_uint(key) & 127u);
}
__device__ __forceinline__ void push2f(float& t1, float& t2, float p) {
    float m = __builtin_amdgcn_fmed3f(t1, t2, p);       // 2nd-largest of {t1>=t2, p}
    t1 = fmaxf(t1, p);
    t2 = m;
}
__device__ __forceinline__ void merge2f(float& t1, float& t2, float o1, float o2) {
    float x = fmaxf(t2, o2);
    float m = __builtin_amdgcn_fmed3f(t1, o1, x);       // 2nd-largest of union
    t1 = fmaxf(t1, o1);
    t2 = m;
}
// ---- exact monotone pack for the repair path (value sign varies) ----
__device__ __forceinline__ unsigned mono32(float v) {
    unsigned u = __float_as_uint(v);
    return u ^ ((u & 0x80000000u) ? 0xFFFFFFFFu : 0x80000000u);
}
__device__ __forceinline__ float unmono32(unsigned k) {
    unsigned u = (k & 0x80000000u) ? (k ^ 0x80000000u) : ~k;
    return __uint_as_float(u);
}
__device__ __forceinline__ unsigned long long pack64(float d, unsigned idx) {
    return ((unsigned long long)mono32(d) << 32) | (unsigned)(~idx);
}

// fp32 -> f16 staging (R15 lesson: direct fp32 fragment loads double the load
// count and blow L2 -> 2x sim time; the 6us staging kernel pays for itself).
__global__ __launch_bounds__(256) void convert_kernel(const float* __restrict__ A,
                                                      const float* __restrict__ B) {
    int t = blockIdx.x * blockDim.x + threadIdx.x;
    const int perMat = N1 * (DK / 4);
    int which = (t >= perMat) ? 1 : 0;
    const float* src = which ? B : A;
    _Float16* dst = which ? g_Bf : g_Af;
    int i = which ? t - perMat : t;
    int m = i >> 5;
    int kq = i & 31;
    float4 v = *reinterpret_cast<const float4*>(src + (size_t)m * DK + kq * 4);
    half4 h = {(_Float16)v.x, (_Float16)v.y, (_Float16)v.z, (_Float16)v.w};
    *reinterpret_cast<half4*>(dst + (size_t)m * DK + kq * 4) = h;
}

// 128x128 tile per block, 4 waves, direct-global f16 fragments (R8/R11 regime),
// XCD swizzle, LDS-merged 128-group top2 with cheap biased-float keys.
// No min-waves bound (R9/R13: min-waves=4 spills acc -> 27MB scratch traffic).
__global__ __launch_bounds__(256) void simf16_kernel() {
    __shared__ float2 lmerge[2][128];   // 1 KB x2

    const int tid  = threadIdx.x;
    const int lane = tid & 63;
    const int wave = tid >> 6;
    const int wm = wave >> 1, wn = wave & 1;
    const int fr = lane & 15, q = lane >> 4;

    // XCD swizzle: dispatch-neighbors (round-robin over 8 XCDs) share ty,
    // clustered tx -> per-XCD L2 panel reuse.
    const int flat = blockIdx.y * 64 + blockIdx.x;
    const int xcd = flat & 7;
    const int j = flat >> 3;
    const int ty = j >> 3;
    const int tx = ((j & 7) << 3) | xcd;
    const int row0 = ty * 128, col0 = tx * 128;

    floatx4 acc[4][4];
#pragma unroll
    for (int mt = 0; mt < 4; ++mt)
#pragma unroll
        for (int nt = 0; nt < 4; ++nt)
            acc[mt][nt] = (floatx4){0.f, 0.f, 0.f, 0.f};

    const _Float16* Ab = g_Af + (size_t)(row0 + wm * 64 + fr) * DK + q * 8;
    const _Float16* Bb = g_Bf + (size_t)(col0 + wn * 64 + fr) * DK + q * 8;

#pragma unroll
    for (int ks = 0; ks < 4; ++ks) {
        half8 af[4], bf[4];
#pragma unroll
        for (int mt = 0; mt < 4; ++mt)
            af[mt] = *reinterpret_cast<const half8*>(Ab + mt * 16 * DK + ks * 32);
#pragma unroll
        for (int nt = 0; nt < 4; ++nt)
            bf[nt] = *reinterpret_cast<const half8*>(Bb + nt * 16 * DK + ks * 32);
#pragma unroll
        for (int mt = 0; mt < 4; ++mt)
#pragma unroll
            for (int nt = 0; nt < 4; ++nt)
                acc[mt][nt] = __builtin_amdgcn_mfma_f32_16x16x32_f16(af[mt], bf[nt], acc[mt][nt], 0, 0, 0);
    }

    // ---- row phase: top2 over 128 cols (C/D: col=lane&15, row=q*4+reg) ----
#pragma unroll
    for (int mt = 0; mt < 4; ++mt) {
#pragma unroll
        for (int reg = 0; reg < 4; ++reg) {
            float t1 = 0.f, t2 = 0.f;
#pragma unroll
            for (int nt = 0; nt < 4; ++nt)
                push2f(t1, t2, bkey(acc[mt][nt][reg], (unsigned)(wn * 64 + nt * 16 + fr)));
#pragma unroll
            for (int off = 1; off < 16; off <<= 1) {
                float o1 = __shfl_xor(t1, off, 64);
                float o2 = __shfl_xor(t2, off, 64);
                merge2f(t1, t2, o1, o2);
            }
            if (fr == 0) lmerge[wn][wm * 64 + mt * 16 + q * 4 + reg] = make_float2(t1, t2);
        }
    }
    __syncthreads();
    if (tid < 128) {
        float2 a = lmerge[0][tid], b = lmerge[1][tid];
        merge2f(a.x, a.y, b.x, b.y);
        g_rowtop2[(size_t)tx * N1 + row0 + tid] = a;   // contiguous 1 KB run
    }
    __syncthreads();

    // ---- col phase: top2 over 128 rows ----
#pragma unroll
    for (int nt = 0; nt < 4; ++nt) {
        float t1 = 0.f, t2 = 0.f;
#pragma unroll
        for (int mt = 0; mt < 4; ++mt)
#pragma unroll
            for (int reg = 0; reg < 4; ++reg)
                push2f(t1, t2, bkey(acc[mt][nt][reg], (unsigned)(wm * 64 + mt * 16 + q * 4 + reg)));
        float o1 = __shfl_xor(t1, 16, 64), o2 = __shfl_xor(t2, 16, 64);
        merge2f(t1, t2, o1, o2);
        o1 = __shfl_xor(t1, 32, 64); o2 = __shfl_xor(t2, 32, 64);
        merge2f(t1, t2, o1, o2);
        if (q == 0) lmerge[wm][wn * 64 + nt * 16 + fr] = make_float2(t1, t2);
    }
    __syncthreads();
    if (tid < 128) {
        float2 a = lmerge[0][tid], b = lmerge[1][tid];
        merge2f(a.x, a.y, b.x, b.y);
        g_coltop2[(size_t)ty * N2 + col0 + tid] = a;
    }
}

// 16 cols per block (512 blocks). Candidates within TAU of approx max get the
// fp32 SEQUENTIAL k-ascending fmaf chain (bitwise reference rounding, R6-proven).
__global__ __launch_bounds__(256) void colfix_kernel(const float* __restrict__ A,
                                                     const float* __restrict__ B) {
    __shared__ float2 tile[64 * 16];          // 8 KB
    __shared__ unsigned long long slot[16];
    __shared__ int cand[256];
    __shared__ int cand_cnt;

    const int tid = threadIdx.x;
    const int c0 = blockIdx.x * 16;

#pragma unroll
    for (int i = 0; i < 4; ++i) {
        int idx = i * 256 + tid;              // 0..1023
        int grp = idx >> 4, c = idx & 15;
        tile[grp * 16 + c] = g_coltop2[(size_t)grp * N2 + c0 + c];
    }
    if (tid < 16) slot[tid] = 0ULL;
    if (tid == 0) cand_cnt = 0;
    __syncthreads();

    const int c = tid >> 4, j = tid & 15;     // 16 threads per col, 4 grps each
    float mx = 0.f;                           // biased domain, all keys > 0
#pragma unroll
    for (int s = 0; s < 4; ++s)
        mx = fmaxf(mx, tile[(j * 4 + s) * 16 + c].x);
    mx = fmaxf(mx, __shfl_xor(mx, 1, 64));
    mx = fmaxf(mx, __shfl_xor(mx, 2, 64));
    mx = fmaxf(mx, __shfl_xor(mx, 4, 64));
    mx = fmaxf(mx, __shfl_xor(mx, 8, 64));
    const float thr = bval(mx) - TAU;         // biased-domain threshold
#pragma unroll
    for (int s = 0; s < 4; ++s) {
        int grp = j * 4 + s;
        float2 e = tile[grp * 16 + c];
        if (bval(e.x) >= thr) {
            int rr = grp * 128 + bidx(e.x);
            int si = atomicAdd(&cand_cnt, 1);
            if (si < 256) cand[si] = (c << 16) | rr;
        }
        if (bval(e.y) >= thr) {
            int rr = grp * 128 + bidx(e.y);
            int si = atomicAdd(&cand_cnt, 1);
            if (si < 256) cand[si] = (c << 16) | rr;
        }
    }
    __syncthreads();

    const int nc = min(cand_cnt, 256);
    for (int i = tid; i < nc; i += 256) {
        int pc = cand[i];
        int cl = pc >> 16, rr = pc & 0xFFFF;
        const float* ar = A + (size_t)rr * DK;
        const float* br = B + (size_t)(c0 + cl) * DK;
        float d = 0.0f;
#pragma unroll
        for (int k4 = 0; k4 < DK / 4; ++k4) {
            float4 a = *reinterpret_cast<const float4*>(ar + k4 * 4);
            float4 b = *reinterpret_cast<const float4*>(br + k4 * 4);
            d = fmaf(a.x, b.x, d);
            d = fmaf(a.y, b.y, d);
            d = fmaf(a.z, b.z, d);
            d = fmaf(a.w, b.w, d);
        }
        atomicMax(&slot[cl], pack64(d, (unsigned)rr));
    }
    __syncthreads();

    if (tid < 16) g_nn21[c0 + tid] = (int)(~(unsigned)slot[tid]);
}

// 16 rows per block (512 blocks). Same repair; fuses mutual check (g_nn21
// complete from the prior colfix launch) and writes both outputs.
__global__ __launch_bounds__(256) void rowfix_mutual_kernel(const float* __restrict__ A,
                                                            const float* __restrict__ B,
                                                            float* __restrict__ out) {
    __shared__ float2 tile[64 * 16];
    __shared__ unsigned long long slot[16];
    __shared__ int cand[256];
    __shared__ int cand_cnt;

    const int tid = threadIdx.x;
    const int r0 = blockIdx.x * 16;

#pragma unroll
    for (int i = 0; i < 4; ++i) {
        int idx = i * 256 + tid;
        int grp = idx >> 4, r = idx & 15;
        tile[grp * 16 + r] = g_rowtop2[(size_t)grp * N1 + r0 + r];
    }
    if (tid < 16) slot[tid] = 0ULL;
    if (tid == 0) cand_cnt = 0;
    __syncthreads();

    const int r = tid >> 4, j = tid & 15;
    float mx = 0.f;
#pragma unroll
    for (int s = 0; s < 4; ++s)
        mx = fmaxf(mx, tile[(j * 4 + s) * 16 + r].x);
    mx = fmaxf(mx, __shfl_xor(mx, 1, 64));
    mx = fmaxf(mx, __shfl_xor(mx, 2, 64));
    mx = fmaxf(mx, __shfl_xor(mx, 4, 64));
    mx = fmaxf(mx, __shfl_xor(mx, 8, 64));
    const float thr = bval(mx) - TAU;
#pragma unroll
    for (int s = 0; s < 4; ++s) {
        int grp = j * 4 + s;
        float2 e = tile[grp * 16 + r];
        if (bval(e.x) >= thr) {
            int cc = grp * 128 + bidx(e.x);
            int si = atomicAdd(&cand_cnt, 1);
            if (si < 256) cand[si] = (r << 16) | cc;
        }
        if (bval(e.y) >= thr) {
            int cc = grp * 128 + bidx(e.y);
            int si = atomicAdd(&cand_cnt, 1);
            if (si < 256) cand[si] = (r << 16) | cc;
        }
    }
    __syncthreads();

    const int nc = min(cand_cnt, 256);
    for (int i = tid; i < nc; i += 256) {
        int pc = cand[i];
        int rl = pc >> 16, cc = pc & 0xFFFF;
        const float* ar = A + (size_t)(r0 + rl) * DK;
        const float* br = B + (size_t)cc * DK;
        float d = 0.0f;
#pragma unroll
        for (int k4 = 0; k4 < DK / 4; ++k4) {
            float4 a = *reinterpret_cast<const float4*>(ar + k4 * 4);
            float4 b = *reinterpret_cast<const float4*>(br + k4 * 4);
            d = fmaf(a.x, b.x, d);
            d = fmaf(a.y, b.y, d);
            d = fmaf(a.z, b.z, d);
            d = fmaf(a.w, b.w, d);
        }
        atomicMax(&slot[rl], pack64(d, (unsigned)cc));
    }
    __syncthreads();

    if (tid < 16) {
        unsigned long long p = slot[tid];
        int row = r0 + tid;
        int m = (int)(~(unsigned)p);
        out[row] = (float)((g_nn21[m] == row) ? m : -1);     // matches0
        out[N1 + row] = unmono32((unsigned)(p >> 32));       // exact score
    }
}

extern "C" void kernel_launch(void* const* d_in, const int* in_sizes, int n_in,
                              void* d_out, int out_size, void* d_ws, size_t ws_size,
                              hipStream_t stream) {
    const float* A = (const float*)d_in[0];   // desc1 [8192,128] f32
    const float* B = (const float*)d_in[1];   // desc2 [8192,128] f32
    float* out = (float*)d_out;               // [0:8192]=matches, [8192:16384]=scores

    convert_kernel<<<2 * N1 * (DK / 4) / 256, 256, 0, stream>>>(A, B);
    dim3 grid(64, 64);
    simf16_kernel<<<grid, 256, 0, stream>>>();
    colfix_kernel<<<N2 / 16, 256, 0, stream>>>(A, B);
    rowfix_mutual_kernel<<<N1 / 16, 256, 0, stream>>>(A, B, out);
}